// Round 7
// baseline (1061.730 us; speedup 1.0000x reference)
//
#include <hip/hip_runtime.h>
#include <hip/hip_bf16.h>

#define NEG_SLOPE 0.2f
#define LOG2E 1.4426950408889634f

// Binning: ~120 dst nodes per bin so per-bin LDS accumulators fit in 64KB.
#define BIN_NODES 120
#define BIN_CAP   2048      // mean load 1199, sigma ~35 -> +24 sigma headroom

typedef __bf16 v8bf __attribute__((ext_vector_type(8)));
typedef float  v4f  __attribute__((ext_vector_type(4)));

static __device__ __forceinline__ unsigned short f2b(float f) {
    unsigned u = __builtin_bit_cast(unsigned, f);
    u += 0x7FFFu + ((u >> 16) & 1u);           // RNE to bf16
    return (unsigned short)(u >> 16);
}
static __device__ __forceinline__ void b2f2(unsigned u, float& lo, float& hi) {
    lo = __builtin_bit_cast(float, u << 16);
    hi = __builtin_bit_cast(float, u & 0xFFFF0000u);
}
static __device__ __forceinline__ void unpack8(uint4 u, float* f) {
    b2f2(u.x, f[0], f[1]); b2f2(u.y, f[2], f[3]);
    b2f2(u.z, f[4], f[5]); b2f2(u.w, f[6], f[7]);
}
static __device__ __forceinline__ int atomIncI(int* p) {
    return __hip_atomic_fetch_add(p, 1, __ATOMIC_RELAXED, __HIP_MEMORY_SCOPE_AGENT);
}

// ---------------------------------------------------------------------------
// kA: fused weight-pack (blocks 0..191) + zero bin cursors (rest).
// Cursors are padded to one per 64B line: 1M atomics over 834 lines
// serialize per-line at ~20cyc/op -> ~11us total (R5 lesson: line-parallel).
// ---------------------------------------------------------------------------
__global__ __launch_bounds__(256) void kA_prep(
    const float* __restrict__ Wl, const float* __restrict__ Wr,
    const float* __restrict__ Ws, unsigned short* __restrict__ Wt,
    int* __restrict__ zero_region, int nzero)
{
    int b = blockIdx.x;
    if (b < 192) {
        int t = b * 256 + threadIdx.x;          // < 49152
        int nn = t >> 7, k = t & 127;
        const float* W = (nn < 128) ? Wl : ((nn < 256) ? Wr : Ws);
        Wt[t] = f2b(W[k * 128 + (nn & 127)]);
    } else {
        int t = (b - 192) * 256 + threadIdx.x;
        if (t < nzero) zero_region[t] = 0;
    }
}

// ---------------------------------------------------------------------------
// kB: fused edge-binning scatter (blocks < KB_SB) + node GEMM (rest).
// Binning: bin = dst/BIN_NODES; pos = cursor[bin]++ (padded cursors);
//          binned[bin*CAP+pos] = (src,dst). No exact CSR needed: the
//          aggregation is commutative, only dst-LOCALITY matters.
// GEMM: 32 nodes/block, 4 waves; wave w owns feats [96w,96w+96);
//       acc = 48 regs/wave (68 VGPR total, ~28% occupancy — R5-verified).
//       LDS [32][136] bf16 staging; MFMA A=weights B=nodes -> packed stores.
// ---------------------------------------------------------------------------
#define KB_SB 512

__global__ __launch_bounds__(256) void kB_bin_gemm(
    const int* __restrict__ ei, int E,
    int* __restrict__ cursors, int2* __restrict__ binned,
    const float* __restrict__ x, const float* __restrict__ tf,
    const unsigned short* __restrict__ Wt,
    const float* __restrict__ bg, const float* __restrict__ bs,
    unsigned short* __restrict__ xl_b, unsigned short* __restrict__ xr_b,
    unsigned short* __restrict__ sk_b, int N)
{
    __shared__ unsigned short lds[32 * 136];
    const int tid = threadIdx.x;

    if (blockIdx.x < KB_SB) {
        const int stride = KB_SB * 256;
        for (int e = blockIdx.x * 256 + tid; e < E; e += stride) {
            int src = ei[e];
            int dst = ei[E + e];
            int bin = dst / BIN_NODES;
            int pos = atomIncI(&cursors[bin * 16]);   // 16 ints = 64B padding
            if (pos < BIN_CAP)
                binned[(size_t)bin * BIN_CAP + pos] = make_int2(src, dst);
        }
        return;
    }

    const int tb = (int)blockIdx.x - KB_SB;
    const int base = tb * 32;

    // ---- stage 32 node rows (x||tf) into LDS as bf16, rows padded to 136 ----
    #pragma unroll
    for (int t = 0; t < 8; ++t) {
        int idx = tid + t * 256;                 // 0..2015 = 32 rows x 63 float2
        if (idx < 2016) {
            int row = idx / 63;
            int c = idx - row * 63;
            int gr = base + row; if (gr >= N) gr = N - 1;
            float2 v = *reinterpret_cast<const float2*>(x + (size_t)gr * 126 + 2 * c);
            unsigned u = (unsigned)f2b(v.x) | ((unsigned)f2b(v.y) << 16);
            *reinterpret_cast<unsigned*>(&lds[row * 136 + 2 * c]) = u;
        }
    }
    if (tid < 32) {
        int gr = base + tid; if (gr >= N) gr = N - 1;
        float2 v = *reinterpret_cast<const float2*>(tf + (size_t)gr * 2);
        unsigned u = (unsigned)f2b(v.x) | ((unsigned)f2b(v.y) << 16);
        *reinterpret_cast<unsigned*>(&lds[tid * 136 + 126]) = u;
    }
    __syncthreads();

    const int wv = tid >> 6;                     // wave 0..3: feats 96w..96w+95
    const int lane = tid & 63;
    const int nidx = lane & 15, quad = lane >> 4;
    const int fbase = wv * 96;

    v4f acc[6][2];                               // [feat-frag][node-frag]
    #pragma unroll
    for (int a = 0; a < 6; ++a)
        #pragma unroll
        for (int b = 0; b < 2; ++b) acc[a][b] = 0.0f;

    #pragma unroll
    for (int ks = 0; ks < 4; ++ks) {
        v8bf bfr[2];
        #pragma unroll
        for (int nf = 0; nf < 2; ++nf)
            bfr[nf] = *reinterpret_cast<const v8bf*>(
                &lds[(nf * 16 + nidx) * 136 + ks * 32 + quad * 8]);
        #pragma unroll
        for (int ft = 0; ft < 6; ++ft) {
            v8bf afr = *reinterpret_cast<const v8bf*>(
                Wt + (size_t)(fbase + ft * 16 + nidx) * 128 + ks * 32 + quad * 8);
            #pragma unroll
            for (int nf = 0; nf < 2; ++nf)
                acc[ft][nf] = __builtin_amdgcn_mfma_f32_16x16x32_bf16(
                    afr, bfr[nf], acc[ft][nf], 0, 0, 0);
        }
    }

    // epilogue: frag f -> array f>>7 (0=xl,1=xr,2=sk), col f&127.
    #pragma unroll
    for (int ft = 0; ft < 6; ++ft) {
        const int f = fbase + ft * 16;
        const int arr = f >> 7;
        const int col = (f & 127) + quad * 4;
        float b0 = 0.0f, b1 = 0.0f, b2 = 0.0f, b3 = 0.0f;
        if (arr == 2) {                           // sk gets bs + bias_gat
            float4 v1 = *reinterpret_cast<const float4*>(bs + (f & 127) + quad * 4);
            float4 v2 = *reinterpret_cast<const float4*>(bg + (f & 127) + quad * 4);
            b0 = v1.x + v2.x; b1 = v1.y + v2.y; b2 = v1.z + v2.z; b3 = v1.w + v2.w;
        }
        unsigned short* dst = (arr == 0) ? xl_b : ((arr == 1) ? xr_b : sk_b);
        #pragma unroll
        for (int nf = 0; nf < 2; ++nf) {
            int node = base + nf * 16 + nidx;
            if (node < N) {
                v4f v = acc[ft][nf];
                uint2 p;
                p.x = (unsigned)f2b(v[0] + b0) | ((unsigned)f2b(v[1] + b1) << 16);
                p.y = (unsigned)f2b(v[2] + b2) | ((unsigned)f2b(v[3] + b3) << 16);
                *reinterpret_cast<uint2*>(dst + (size_t)node * 128 + col) = p;
            }
        }
    }
}

// ---------------------------------------------------------------------------
// kE: one block per bin. LDS holds per-dst accumulators (120 x 128 fp32 +
// denom), edges of the bin are read COALESCED, xl gathered 16B/lane with
// 2 edges in flight per 16-lane group, e*xl accumulated via ds_add_f32.
// Epilogue fuses self-loop + divide + skip + ELU + Wo dot + sigmoid.
// Replaces hist/scan/scatter/k2 (no global atomics beyond the bin cursors).
// ---------------------------------------------------------------------------
__global__ __launch_bounds__(256) void kE_binagg(
    const int* __restrict__ cursors, const int2* __restrict__ binned,
    const unsigned short* __restrict__ xl_b,
    const unsigned short* __restrict__ xr_b,
    const unsigned short* __restrict__ sk_b,
    const float* __restrict__ att,
    const float* __restrict__ Wo, const float* __restrict__ bo,
    float* __restrict__ out, int N)
{
    __shared__ float acc_s[BIN_NODES * 128];    // 61440 B
    __shared__ float den_s[BIN_NODES * 8];      //  3840 B  (total 65280 <= 64K)
    const int tid = threadIdx.x;
    const int bin = blockIdx.x;
    const int base = bin * BIN_NODES;

    #pragma unroll
    for (int i = 0; i < 60; ++i) acc_s[tid + i * 256] = 0.0f;
    for (int i = tid; i < BIN_NODES * 8; i += 256) den_s[i] = 0.0f;
    __syncthreads();

    const int g = tid >> 4;                     // 16 groups of 16 lanes
    const int j = tid & 15;
    const int cb = j * 8;                       // cols cb..cb+7, head = j>>1

    float4 a0 = *reinterpret_cast<const float4*>(att + cb);
    float4 a1 = *reinterpret_cast<const float4*>(att + cb + 4);
    float av[8] = {a0.x * LOG2E, a0.y * LOG2E, a0.z * LOG2E, a0.w * LOG2E,
                   a1.x * LOG2E, a1.y * LOG2E, a1.z * LOG2E, a1.w * LOG2E};

    int count = cursors[bin * 16];
    if (count > BIN_CAP) count = BIN_CAP;
    const int2* ebase = binned + (size_t)bin * BIN_CAP;

    auto procEdge = [&](int2 ed) {
        float xl[8], xr[8];
        unpack8(*reinterpret_cast<const uint4*>(xl_b + (size_t)ed.x * 128 + cb), xl);
        unpack8(*reinterpret_cast<const uint4*>(xr_b + (size_t)ed.y * 128 + cb), xr);
        float t = 0.0f;
        #pragma unroll
        for (int c = 0; c < 8; ++c) {
            float m = xl[c] + xr[c];
            float l = fmaxf(m, NEG_SLOPE * m);
            t = fmaf(l, av[c], t);
        }
        t += __shfl_xor(t, 1, 64);              // close 16-col head dot
        float e = exp2f(t);
        int d = ed.y - base;
        float* ap = &acc_s[d * 128 + cb];
        #pragma unroll
        for (int c = 0; c < 8; ++c) atomicAdd(&ap[c], e * xl[c]);
        if ((j & 1) == 0) atomicAdd(&den_s[d * 8 + (j >> 1)], e);
    };

    // 2 edges in flight per group for gather-latency overlap
    int ii = g;
    for (; ii + 16 < count; ii += 32) {
        int2 e0 = ebase[ii];
        int2 e1 = ebase[ii + 16];
        procEdge(e0);
        procEdge(e1);
    }
    if (ii < count) procEdge(ebase[ii]);
    __syncthreads();

    // epilogue: self-loop + finalize, one 16-lane group per dst
    for (int d = g; d < BIN_NODES; d += 16) {
        const int node = base + d;
        if (node >= N) continue;
        float xl[8], xr[8], sk[8];
        unpack8(*reinterpret_cast<const uint4*>(xl_b + (size_t)node * 128 + cb), xl);
        unpack8(*reinterpret_cast<const uint4*>(xr_b + (size_t)node * 128 + cb), xr);
        float t = 0.0f;
        #pragma unroll
        for (int c = 0; c < 8; ++c) {
            float m = xl[c] + xr[c];
            float l = fmaxf(m, NEG_SLOPE * m);
            t = fmaf(l, av[c], t);
        }
        t += __shfl_xor(t, 1, 64);
        float e = exp2f(t);                     // self-loop weight
        float den = den_s[d * 8 + (j >> 1)] + e;
        float rd = 1.0f / (den + 1e-16f);
        unpack8(*reinterpret_cast<const uint4*>(sk_b + (size_t)node * 128 + cb), sk);
        float4 w0 = *reinterpret_cast<const float4*>(Wo + cb);
        float4 w1 = *reinterpret_cast<const float4*>(Wo + cb + 4);
        float wv[8] = {w0.x, w0.y, w0.z, w0.w, w1.x, w1.y, w1.z, w1.w};
        float s = 0.0f;
        #pragma unroll
        for (int c = 0; c < 8; ++c) {
            float a = acc_s[d * 128 + cb + c] + e * xl[c];
            float gg = fmaf(a, rd, sk[c]);
            float el = gg > 0.0f ? gg : (exp2f(gg * LOG2E) - 1.0f);
            s = fmaf(el, wv[c], s);
        }
        s += __shfl_xor(s, 1, 64);
        s += __shfl_xor(s, 2, 64);
        s += __shfl_xor(s, 4, 64);
        s += __shfl_xor(s, 8, 64);
        if (j == 0) {
            float z = s + bo[0];
            out[node] = 1.0f / (1.0f + exp2f(-z * LOG2E));
        }
    }
}

// ---------------------------------------------------------------------------
extern "C" void kernel_launch(void* const* d_in, const int* in_sizes, int n_in,
                              void* d_out, int out_size, void* d_ws, size_t ws_size,
                              hipStream_t stream) {
    const float* x   = (const float*)d_in[0];
    const float* tf  = (const float*)d_in[1];
    const int*   ei  = (const int*)  d_in[2];
    const float* Wl  = (const float*)d_in[3];
    const float* Wr  = (const float*)d_in[4];
    const float* att = (const float*)d_in[5];
    const float* bg  = (const float*)d_in[6];
    const float* Ws  = (const float*)d_in[7];
    const float* bs  = (const float*)d_in[8];
    const float* Wo  = (const float*)d_in[9];
    const float* bo  = (const float*)d_in[10];
    float* out = (float*)d_out;

    const int N = in_sizes[0] / 126;
    const int E = in_sizes[2] / 2;
    const int nbins = (N + BIN_NODES - 1) / BIN_NODES;   // 834 for N=100000

    char* ws = (char*)d_ws;
    unsigned short* Wt   = (unsigned short*)ws; ws += (size_t)384 * 128 * 2;
    unsigned short* xl_b = (unsigned short*)ws; ws += (size_t)N * 128 * 2;
    unsigned short* xr_b = (unsigned short*)ws; ws += (size_t)N * 128 * 2;
    unsigned short* sk_b = (unsigned short*)ws; ws += (size_t)N * 128 * 2;
    int*  cursors = (int*)ws;  ws += (size_t)nbins * 16 * 4;   // 64B-padded
    int2* binned  = (int2*)ws; ws += (size_t)nbins * BIN_CAP * 8;  // ~13.7 MB

    // 1: weight pack + zero cursors
    const int nzero = nbins * 16;
    hipLaunchKernelGGL(kA_prep, dim3(192 + (nzero + 255) / 256), dim3(256), 0, stream,
                       Wl, Wr, Ws, Wt, cursors, nzero);
    // 2: edge binning (atomic/latency-bound) fused with node GEMM
    const int GB = (N + 31) / 32;
    hipLaunchKernelGGL(kB_bin_gemm, dim3(KB_SB + GB), dim3(256), 0, stream,
                       ei, E, cursors, binned, x, tf, Wt, bg, bs,
                       xl_b, xr_b, sk_b, N);
    // 3: per-bin LDS aggregation + fused finalize
    hipLaunchKernelGGL(kE_binagg, dim3(nbins), dim3(256), 0, stream,
                       cursors, binned, xl_b, xr_b, sk_b, att, Wo, bo, out, N);
}

// Round 8
// 286.286 us; speedup vs baseline: 3.7086x; 3.7086x over previous
//
#include <hip/hip_runtime.h>
#include <hip/hip_bf16.h>

#define NEG_SLOPE 0.2f
#define LOG2E 1.4426950408889634f

typedef __bf16 v8bf __attribute__((ext_vector_type(8)));
typedef float  v4f  __attribute__((ext_vector_type(4)));

static __device__ __forceinline__ unsigned short f2b(float f) {
    unsigned u = __builtin_bit_cast(unsigned, f);
    u += 0x7FFFu + ((u >> 16) & 1u);           // RNE to bf16
    return (unsigned short)(u >> 16);
}
static __device__ __forceinline__ void b2f2(unsigned u, float& lo, float& hi) {
    lo = __builtin_bit_cast(float, u << 16);
    hi = __builtin_bit_cast(float, u & 0xFFFF0000u);
}
static __device__ __forceinline__ void unpack8(uint4 u, float* f) {
    b2f2(u.x, f[0], f[1]); b2f2(u.y, f[2], f[3]);
    b2f2(u.z, f[4], f[5]); b2f2(u.w, f[6], f[7]);
}
static __device__ __forceinline__ int atomIncI(int* p) {
    return __hip_atomic_fetch_add(p, 1, __ATOMIC_RELAXED, __HIP_MEMORY_SCOPE_AGENT);
}

// ---------------------------------------------------------------------------
// kA: fused weight-pack (blocks 0..191) + zero counts (rest).
// Wt layout: [feat(384)][k(128)] bf16 so MFMA A-frags are contiguous 16B.
// ---------------------------------------------------------------------------
__global__ __launch_bounds__(256) void kA_prep(
    const float* __restrict__ Wl, const float* __restrict__ Wr,
    const float* __restrict__ Ws, unsigned short* __restrict__ Wt,
    int* __restrict__ zero_region, int nzero)
{
    int b = blockIdx.x;
    if (b < 192) {
        int t = b * 256 + threadIdx.x;          // < 49152
        int nn = t >> 7, k = t & 127;
        const float* W = (nn < 128) ? Wl : ((nn < 256) ? Wr : Ws);
        Wt[t] = f2b(W[k * 128 + (nn & 127)]);
    } else {
        int t = (b - 192) * 256 + threadIdx.x;
        if (t < nzero) zero_region[t] = 0;
    }
}

// ---------------------------------------------------------------------------
// kB: fused in-degree histogram+rank (blocks < KB_HB) + node GEMM (rest).
// Hist: rank[e] = counts[dst]++ (atomic return = slot in dst bucket -> the
//       scatter needs no atomics). Scattered-atomic model (R1/R5/R6
//       calibration): ~60-100ns per random line-op -> 1M edges ~= 60-100us;
//       this IS kB's floor. R5 lesson: never concentrate atomics onto few
//       cache lines (391 counters cost 400us). R7 lesson: never trade
//       wave-parallelism for fewer atomics (kE: 3k serial streams = 863us).
// GEMM: 32 nodes/block, 4 waves; wave w owns feats [96w,96w+96);
//       48 acc regs/wave, 68 VGPR total (~28% occ; 128-reg acc tile had
//       collapsed occupancy to 7.7% on the unified VGPR/AGPR file).
// ---------------------------------------------------------------------------
#define KB_HB 512

__global__ __launch_bounds__(256) void kB_hist_gemm(
    const int* __restrict__ ei, int E,
    int* __restrict__ counts, int* __restrict__ rank,
    const float* __restrict__ x, const float* __restrict__ tf,
    const unsigned short* __restrict__ Wt,
    const float* __restrict__ bg, const float* __restrict__ bs,
    unsigned short* __restrict__ xl_b, unsigned short* __restrict__ xr_b,
    unsigned short* __restrict__ sk_b, int N)
{
    __shared__ unsigned short lds[32 * 136];
    const int tid = threadIdx.x;

    if (blockIdx.x < KB_HB) {
        const int stride = KB_HB * 256;
        for (int e = blockIdx.x * 256 + tid; e < E; e += stride) {
            int dst = ei[E + e];
            rank[e] = atomIncI(&counts[dst]);
        }
        return;
    }

    const int tb = (int)blockIdx.x - KB_HB;
    const int base = tb * 32;

    // ---- stage 32 node rows (x||tf) into LDS as bf16, rows padded to 136 ----
    #pragma unroll
    for (int t = 0; t < 8; ++t) {
        int idx = tid + t * 256;                 // 0..2015 = 32 rows x 63 float2
        if (idx < 2016) {
            int row = idx / 63;
            int c = idx - row * 63;
            int gr = base + row; if (gr >= N) gr = N - 1;
            float2 v = *reinterpret_cast<const float2*>(x + (size_t)gr * 126 + 2 * c);
            unsigned u = (unsigned)f2b(v.x) | ((unsigned)f2b(v.y) << 16);
            *reinterpret_cast<unsigned*>(&lds[row * 136 + 2 * c]) = u;
        }
    }
    if (tid < 32) {
        int gr = base + tid; if (gr >= N) gr = N - 1;
        float2 v = *reinterpret_cast<const float2*>(tf + (size_t)gr * 2);
        unsigned u = (unsigned)f2b(v.x) | ((unsigned)f2b(v.y) << 16);
        *reinterpret_cast<unsigned*>(&lds[tid * 136 + 126]) = u;
    }
    __syncthreads();

    const int wv = tid >> 6;                     // wave 0..3: feats 96w..96w+95
    const int lane = tid & 63;
    const int nidx = lane & 15, quad = lane >> 4;
    const int fbase = wv * 96;

    v4f acc[6][2];                               // [feat-frag][node-frag]
    #pragma unroll
    for (int a = 0; a < 6; ++a)
        #pragma unroll
        for (int b = 0; b < 2; ++b) acc[a][b] = 0.0f;

    #pragma unroll
    for (int ks = 0; ks < 4; ++ks) {
        v8bf bfr[2];
        #pragma unroll
        for (int nf = 0; nf < 2; ++nf)
            bfr[nf] = *reinterpret_cast<const v8bf*>(
                &lds[(nf * 16 + nidx) * 136 + ks * 32 + quad * 8]);
        #pragma unroll
        for (int ft = 0; ft < 6; ++ft) {
            v8bf afr = *reinterpret_cast<const v8bf*>(
                Wt + (size_t)(fbase + ft * 16 + nidx) * 128 + ks * 32 + quad * 8);
            #pragma unroll
            for (int nf = 0; nf < 2; ++nf)
                acc[ft][nf] = __builtin_amdgcn_mfma_f32_16x16x32_bf16(
                    afr, bfr[nf], acc[ft][nf], 0, 0, 0);
        }
    }

    // epilogue: frag f -> array f>>7 (0=xl,1=xr,2=sk), col f&127.
    #pragma unroll
    for (int ft = 0; ft < 6; ++ft) {
        const int f = fbase + ft * 16;
        const int arr = f >> 7;
        const int col = (f & 127) + quad * 4;
        float b0 = 0.0f, b1 = 0.0f, b2 = 0.0f, b3 = 0.0f;
        if (arr == 2) {                           // sk gets bs + bias_gat
            float4 v1 = *reinterpret_cast<const float4*>(bs + (f & 127) + quad * 4);
            float4 v2 = *reinterpret_cast<const float4*>(bg + (f & 127) + quad * 4);
            b0 = v1.x + v2.x; b1 = v1.y + v2.y; b2 = v1.z + v2.z; b3 = v1.w + v2.w;
        }
        unsigned short* dst = (arr == 0) ? xl_b : ((arr == 1) ? xr_b : sk_b);
        #pragma unroll
        for (int nf = 0; nf < 2; ++nf) {
            int node = base + nf * 16 + nidx;
            if (node < N) {
                v4f v = acc[ft][nf];
                uint2 p;
                p.x = (unsigned)f2b(v[0] + b0) | ((unsigned)f2b(v[1] + b1) << 16);
                p.y = (unsigned)f2b(v[2] + b2) | ((unsigned)f2b(v[3] + b3) << 16);
                *reinterpret_cast<uint2*>(dst + (size_t)node * 128 + col) = p;
            }
        }
    }
}

// ---------------------------------------------------------------------------
// ks_a: per-256-chunk sums of counts -> partial[NB]
// ---------------------------------------------------------------------------
__global__ __launch_bounds__(256) void ks_a(
    const int* __restrict__ counts, int* __restrict__ partial, int N)
{
    __shared__ int s[256];
    int t = threadIdx.x, i = blockIdx.x * 256 + t;
    s[t] = (i < N) ? counts[i] : 0;
    __syncthreads();
    #pragma unroll
    for (int off = 128; off >= 1; off >>= 1) {
        if (t < off) s[t] += s[t + off];
        __syncthreads();
    }
    if (t == 0) partial[blockIdx.x] = s[0];
}

// ---------------------------------------------------------------------------
// ks_bc: merged global+local scan -> range[i] = (start, count).
// ---------------------------------------------------------------------------
__global__ __launch_bounds__(1024) void ks_bc(
    const int* __restrict__ counts, const int* __restrict__ partial,
    int2* __restrict__ range, int N, int NB)
{
    __shared__ int sp[1024];
    __shared__ int sc[256];
    const int t = threadIdx.x;
    sp[t] = (t < NB) ? partial[t] : 0;
    __syncthreads();
    #pragma unroll
    for (int off = 1; off < 1024; off <<= 1) {
        int v = (t >= off) ? sp[t - off] : 0;
        __syncthreads();
        sp[t] += v;
        __syncthreads();
    }
    const int blockbase = (blockIdx.x == 0) ? 0 : sp[blockIdx.x - 1];

    const int i = blockIdx.x * 256 + (t & 255);
    int c = 0;
    if (t < 256) {
        c = (i < N) ? counts[i] : 0;
        sc[t] = c;
    }
    __syncthreads();
    #pragma unroll
    for (int off = 1; off < 256; off <<= 1) {
        int v = 0;
        if (t < 256 && t >= off) v = sc[t - off];
        __syncthreads();
        if (t < 256) sc[t] += v;
        __syncthreads();
    }
    if (t < 256 && i < N)
        range[i] = make_int2(blockbase + sc[t] - c, c);   // exclusive start, count
}

// ---------------------------------------------------------------------------
// kD: atomic-free CSR scatter: sorted_src[range[dst].x + rank[e]] = src.
// One edge/thread, full grid: maximize outstanding stores (random 4B writes
// are RFO-bound; more waves = more lines in flight).
// ---------------------------------------------------------------------------
__global__ __launch_bounds__(256) void kD_scatter(
    const int* __restrict__ ei, int E,
    const int2* __restrict__ range, const int* __restrict__ rank,
    int* __restrict__ sorted_src)
{
    int e = blockIdx.x * 256 + threadIdx.x;
    if (e < E) {
        int src = ei[e];
        int dst = ei[E + e];
        sorted_src[range[dst].x + rank[e]] = src;
    }
}

// ---------------------------------------------------------------------------
// k2: fused segment-reduce + finalize. One wave per dst node; 4 edge-slots
// of 16 lanes; lane j covers cols 8j..8j+7 via one 16B gather.
// 2-stage software pipeline: next slot-group's sorted_src AND xl-gather are
// issued before the current group's shuffle chain closes. Invalid slots
// clamp to src=node (always-safe load, e masked to 0).
// ---------------------------------------------------------------------------
__global__ __launch_bounds__(256, 6) void k2_aggfin(
    const int2* __restrict__ range, const int* __restrict__ sorted_src,
    const unsigned short* __restrict__ xl_b,
    const unsigned short* __restrict__ xr_b,
    const unsigned short* __restrict__ sk_b,
    const float* __restrict__ att,
    const float* __restrict__ Wo, const float* __restrict__ bo,
    float* __restrict__ out, int N)
{
    const int node = (int)((blockIdx.x * (size_t)blockDim.x + threadIdx.x) >> 6);
    const int lane = threadIdx.x & 63;
    if (node >= N) return;
    const int j = lane & 15;                    // col-lane within edge slot
    const int g = lane >> 4;                    // edge slot 0..3
    const int cb = j * 8;                       // first col of this lane

    float4 a0 = *reinterpret_cast<const float4*>(att + cb);
    float4 a1 = *reinterpret_cast<const float4*>(att + cb + 4);
    float av[8] = {a0.x * LOG2E, a0.y * LOG2E, a0.z * LOG2E, a0.w * LOG2E,
                   a1.x * LOG2E, a1.y * LOG2E, a1.z * LOG2E, a1.w * LOG2E};
    float xr[8];
    unpack8(*reinterpret_cast<const uint4*>(xr_b + (size_t)node * 128 + cb), xr);

    float acc[8];
    #pragma unroll
    for (int c = 0; c < 8; ++c) acc[c] = 0.0f;
    float den = 0.0f;

    const int2 rc = range[node];
    const int total = rc.y + 1;                 // + self-loop
    const int srcbase = rc.x - 1;

    auto loadsrc = [&](int b0) -> int {
        int ii = b0 + g;
        int ic = (ii > 0 && ii < total) ? ii : 0;
        return (ic == 0) ? node : sorted_src[srcbase + ic];
    };
    auto gather = [&](int src) -> uint4 {
        return *reinterpret_cast<const uint4*>(xl_b + (size_t)src * 128 + cb);
    };

    int   sB = loadsrc(0);
    uint4 uA = gather(sB);
    sB = loadsrc(4);

    for (int b0 = 0; b0 < total; b0 += 4) {
        uint4 uB = gather(sB);                  // prefetch: next xl (1 iter ahead)
        int   sC = loadsrc(b0 + 8);             // prefetch: src after next (2 ahead)

        bool valid = (b0 + g) < total;
        float xl[8];
        unpack8(uA, xl);
        float t = 0.0f;
        #pragma unroll
        for (int c = 0; c < 8; ++c) {
            float m = xl[c] + xr[c];
            float l = fmaxf(m, NEG_SLOPE * m);  // leaky relu
            t = fmaf(l, av[c], t);
        }
        t += __shfl_xor(t, 1, 64);              // close 16-col head dot
        float e = valid ? exp2f(t) : 0.0f;
        #pragma unroll
        for (int c = 0; c < 8; ++c) acc[c] = fmaf(e, xl[c], acc[c]);
        den += e;

        uA = uB; sB = sC;
    }

    // merge the 4 edge slots (lanes +-16, +-32 hold same cols)
    #pragma unroll
    for (int c = 0; c < 8; ++c) {
        acc[c] += __shfl_xor(acc[c], 16, 64);
        acc[c] += __shfl_xor(acc[c], 32, 64);
    }
    den += __shfl_xor(den, 16, 64);
    den += __shfl_xor(den, 32, 64);

    float rd = 1.0f / (den + 1e-16f);
    float sk[8];
    unpack8(*reinterpret_cast<const uint4*>(sk_b + (size_t)node * 128 + cb), sk);
    float4 w0 = *reinterpret_cast<const float4*>(Wo + cb);
    float4 w1 = *reinterpret_cast<const float4*>(Wo + cb + 4);
    float wv[8] = {w0.x, w0.y, w0.z, w0.w, w1.x, w1.y, w1.z, w1.w};
    float s = 0.0f;
    #pragma unroll
    for (int c = 0; c < 8; ++c) {
        float gg = fmaf(acc[c], rd, sk[c]);
        float el = gg > 0.0f ? gg : (exp2f(gg * LOG2E) - 1.0f);  // elu
        s = fmaf(el, wv[c], s);
    }
    s += __shfl_xor(s, 1, 64);
    s += __shfl_xor(s, 2, 64);
    s += __shfl_xor(s, 4, 64);
    s += __shfl_xor(s, 8, 64);
    if (lane == 0) {
        float z = s + bo[0];
        out[node] = 1.0f / (1.0f + exp2f(-z * LOG2E));
    }
}

// ---------------------------------------------------------------------------
extern "C" void kernel_launch(void* const* d_in, const int* in_sizes, int n_in,
                              void* d_out, int out_size, void* d_ws, size_t ws_size,
                              hipStream_t stream) {
    const float* x   = (const float*)d_in[0];
    const float* tf  = (const float*)d_in[1];
    const int*   ei  = (const int*)  d_in[2];
    const float* Wl  = (const float*)d_in[3];
    const float* Wr  = (const float*)d_in[4];
    const float* att = (const float*)d_in[5];
    const float* bg  = (const float*)d_in[6];
    const float* Ws  = (const float*)d_in[7];
    const float* bs  = (const float*)d_in[8];
    const float* Wo  = (const float*)d_in[9];
    const float* bo  = (const float*)d_in[10];
    float* out = (float*)d_out;

    const int N = in_sizes[0] / 126;
    const int E = in_sizes[2] / 2;
    const int NB = (N + 255) / 256;     // 391 for N=100000 (must be <= 1024)

    char* ws = (char*)d_ws;
    unsigned short* Wt   = (unsigned short*)ws; ws += (size_t)384 * 128 * 2;
    unsigned short* xl_b = (unsigned short*)ws; ws += (size_t)N * 128 * 2;
    unsigned short* xr_b = (unsigned short*)ws; ws += (size_t)N * 128 * 2;
    unsigned short* sk_b = (unsigned short*)ws; ws += (size_t)N * 128 * 2;
    int*  counts   = (int*)ws;  ws += (size_t)N * 4;
    int*  partial  = (int*)ws;  ws += (size_t)1024 * 4;
    int2* range    = (int2*)ws; ws += (size_t)N * 8;
    int*  rank     = (int*)ws;  ws += (size_t)E * 4;
    int*  sorted_src = (int*)ws; ws += (size_t)E * 4;

    // 1: weight pack + zero counts
    hipLaunchKernelGGL(kA_prep, dim3(192 + (N + 255) / 256), dim3(256), 0, stream,
                       Wl, Wr, Ws, Wt, counts, N);
    // 2: histogram+rank (atomic-floor-bound) fused with node GEMM
    const int GB = (N + 31) / 32;
    hipLaunchKernelGGL(kB_hist_gemm, dim3(KB_HB + GB), dim3(256), 0, stream,
                       ei, E, counts, rank, x, tf, Wt, bg, bs,
                       xl_b, xr_b, sk_b, N);
    // 3-4: scan -> range(start,count)
    hipLaunchKernelGGL(ks_a, dim3(NB), dim3(256), 0, stream, counts, partial, N);
    hipLaunchKernelGGL(ks_bc, dim3(NB), dim3(1024), 0, stream,
                       counts, partial, range, N, NB);
    // 5: atomic-free scatter
    hipLaunchKernelGGL(kD_scatter, dim3((E + 255) / 256), dim3(256), 0, stream,
                       ei, E, range, rank, sorted_src);
    // 6: segment-reduce + finalize (pipelined gathers)
    hipLaunchKernelGGL(k2_aggfin, dim3((N + 3) / 4), dim3(256), 0, stream,
                       range, sorted_src, xl_b, xr_b, sk_b,
                       att, Wo, bo, out, N);
}

// Round 9
// 280.568 us; speedup vs baseline: 3.7842x; 1.0204x over previous
//
#include <hip/hip_runtime.h>
#include <hip/hip_bf16.h>

#define NEG_SLOPE 0.2f
#define LOG2E 1.4426950408889634f

typedef __bf16 v8bf __attribute__((ext_vector_type(8)));
typedef float  v4f  __attribute__((ext_vector_type(4)));

static __device__ __forceinline__ unsigned short f2b(float f) {
    unsigned u = __builtin_bit_cast(unsigned, f);
    u += 0x7FFFu + ((u >> 16) & 1u);           // RNE to bf16
    return (unsigned short)(u >> 16);
}
static __device__ __forceinline__ void b2f2(unsigned u, float& lo, float& hi) {
    lo = __builtin_bit_cast(float, u << 16);
    hi = __builtin_bit_cast(float, u & 0xFFFF0000u);
}
static __device__ __forceinline__ void unpack8(uint4 u, float* f) {
    b2f2(u.x, f[0], f[1]); b2f2(u.y, f[2], f[3]);
    b2f2(u.z, f[4], f[5]); b2f2(u.w, f[6], f[7]);
}
static __device__ __forceinline__ int atomIncI(int* p) {
    return __hip_atomic_fetch_add(p, 1, __ATOMIC_RELAXED, __HIP_MEMORY_SCOPE_AGENT);
}

// ---------------------------------------------------------------------------
// kA: fused weight-pack (blocks 0..191) + zero counts (rest).
// Wt layout: [feat(384)][k(128)] bf16 so MFMA A-frags are contiguous 16B.
// ---------------------------------------------------------------------------
__global__ __launch_bounds__(256) void kA_prep(
    const float* __restrict__ Wl, const float* __restrict__ Wr,
    const float* __restrict__ Ws, unsigned short* __restrict__ Wt,
    int* __restrict__ zero_region, int nzero)
{
    int b = blockIdx.x;
    if (b < 192) {
        int t = b * 256 + threadIdx.x;          // < 49152
        int nn = t >> 7, k = t & 127;
        const float* W = (nn < 128) ? Wl : ((nn < 256) ? Wr : Ws);
        Wt[t] = f2b(W[k * 128 + (nn & 127)]);
    } else {
        int t = (b - 192) * 256 + threadIdx.x;
        if (t < nzero) zero_region[t] = 0;
    }
}

// ---------------------------------------------------------------------------
// kB: fused in-degree histogram+rank (blocks < KB_HB) + node GEMM (rest).
// R8 post-mortem: the GEMM (not the hist atomics) is this kernel's floor —
// R2's hist-free GEMM was the same 105us. The old epilogue stored 16
// scattered 32B segments per instr (RFO amp: WRITE 110MB vs 81 useful).
// Fix: LDS-bounce epilogue -> 3 x 8KB fully CONTIGUOUS streams per block.
// Out LDS tile [3][32][132] halves (132 pad kills the 16-way bank conflict
// of the natural 128 stride); aliases the staging tile (barrier-separated).
// GEMM: 32 nodes/block, 4 waves; wave w owns feats [96w,96w+96); 48 acc
// regs/wave (unified VGPR/AGPR file: big acc tiles collapse occupancy).
// ---------------------------------------------------------------------------
#define KB_HB 512

__global__ __launch_bounds__(256) void kB_hist_gemm(
    const int* __restrict__ ei, int E,
    int* __restrict__ counts, int* __restrict__ rank,
    const float* __restrict__ x, const float* __restrict__ tf,
    const unsigned short* __restrict__ Wt,
    const float* __restrict__ bg, const float* __restrict__ bs,
    unsigned short* __restrict__ xl_b, unsigned short* __restrict__ xr_b,
    unsigned short* __restrict__ sk_b, int N)
{
    // staging: [32][136] halves = 4352 halves (first part)
    // out:     [3][32][132] halves = 12672 halves (aliases whole buffer)
    __shared__ unsigned short lds[12672];       // 25344 B
    const int tid = threadIdx.x;

    if (blockIdx.x < KB_HB) {
        const int stride = KB_HB * 256;
        for (int e = blockIdx.x * 256 + tid; e < E; e += stride) {
            int dst = ei[E + e];
            rank[e] = atomIncI(&counts[dst]);
        }
        return;
    }

    const int tb = (int)blockIdx.x - KB_HB;
    const int base = tb * 32;

    // ---- stage 32 node rows (x||tf) into LDS as bf16, rows padded to 136 ----
    #pragma unroll
    for (int t = 0; t < 8; ++t) {
        int idx = tid + t * 256;                 // 0..2015 = 32 rows x 63 float2
        if (idx < 2016) {
            int row = idx / 63;
            int c = idx - row * 63;
            int gr = base + row; if (gr >= N) gr = N - 1;
            float2 v = *reinterpret_cast<const float2*>(x + (size_t)gr * 126 + 2 * c);
            unsigned u = (unsigned)f2b(v.x) | ((unsigned)f2b(v.y) << 16);
            *reinterpret_cast<unsigned*>(&lds[row * 136 + 2 * c]) = u;
        }
    }
    if (tid < 32) {
        int gr = base + tid; if (gr >= N) gr = N - 1;
        float2 v = *reinterpret_cast<const float2*>(tf + (size_t)gr * 2);
        unsigned u = (unsigned)f2b(v.x) | ((unsigned)f2b(v.y) << 16);
        *reinterpret_cast<unsigned*>(&lds[tid * 136 + 126]) = u;
    }
    __syncthreads();

    const int wv = tid >> 6;                     // wave 0..3: feats 96w..96w+95
    const int lane = tid & 63;
    const int nidx = lane & 15, quad = lane >> 4;
    const int fbase = wv * 96;

    v4f acc[6][2];                               // [feat-frag][node-frag]
    #pragma unroll
    for (int a = 0; a < 6; ++a)
        #pragma unroll
        for (int b = 0; b < 2; ++b) acc[a][b] = 0.0f;

    #pragma unroll
    for (int ks = 0; ks < 4; ++ks) {
        v8bf bfr[2];
        #pragma unroll
        for (int nf = 0; nf < 2; ++nf)
            bfr[nf] = *reinterpret_cast<const v8bf*>(
                &lds[(nf * 16 + nidx) * 136 + ks * 32 + quad * 8]);
        #pragma unroll
        for (int ft = 0; ft < 6; ++ft) {
            v8bf afr = *reinterpret_cast<const v8bf*>(
                Wt + (size_t)(fbase + ft * 16 + nidx) * 128 + ks * 32 + quad * 8);
            #pragma unroll
            for (int nf = 0; nf < 2; ++nf)
                acc[ft][nf] = __builtin_amdgcn_mfma_f32_16x16x32_bf16(
                    afr, bfr[nf], acc[ft][nf], 0, 0, 0);
        }
    }

    __syncthreads();                             // staging reads done; re-use LDS

    // ---- deposit acc (bias applied) into out tile [arr][node][col pad 132] ----
    #pragma unroll
    for (int ft = 0; ft < 6; ++ft) {
        const int f = fbase + ft * 16;
        const int arr = f >> 7;
        const int colb = (f & 127) + quad * 4;
        float b0 = 0.0f, b1 = 0.0f, b2 = 0.0f, b3 = 0.0f;
        if (arr == 2) {                           // sk gets bs + bias_gat
            float4 v1 = *reinterpret_cast<const float4*>(bs + (f & 127) + quad * 4);
            float4 v2 = *reinterpret_cast<const float4*>(bg + (f & 127) + quad * 4);
            b0 = v1.x + v2.x; b1 = v1.y + v2.y; b2 = v1.z + v2.z; b3 = v1.w + v2.w;
        }
        #pragma unroll
        for (int nf = 0; nf < 2; ++nf) {
            const int nloc = nf * 16 + nidx;
            v4f v = acc[ft][nf];
            uint2 p;
            p.x = (unsigned)f2b(v[0] + b0) | ((unsigned)f2b(v[1] + b1) << 16);
            p.y = (unsigned)f2b(v[2] + b2) | ((unsigned)f2b(v[3] + b3) << 16);
            *reinterpret_cast<uint2*>(&lds[arr * 4224 + nloc * 132 + colb]) = p;
        }
    }
    __syncthreads();

    // ---- cooperative coalesced store: 3 arrays x 512 uint4 (8KB contiguous) --
    #pragma unroll
    for (int it = 0; it < 6; ++it) {
        int i = tid + it * 256;                  // 0..1535
        int arr = i >> 9;
        int idx = i & 511;
        int nloc = idx >> 4;
        int colh = (idx & 15) * 8;
        int node = base + nloc;
        if (node < N) {
            uint4 v = *reinterpret_cast<const uint4*>(&lds[arr * 4224 + nloc * 132 + colh]);
            unsigned short* dp = (arr == 0) ? xl_b : ((arr == 1) ? xr_b : sk_b);
            *reinterpret_cast<uint4*>(dp + (size_t)node * 128 + colh) = v;
        }
    }
}

// ---------------------------------------------------------------------------
// ks_a: per-256-chunk sums of counts -> partial[NB]
// ---------------------------------------------------------------------------
__global__ __launch_bounds__(256) void ks_a(
    const int* __restrict__ counts, int* __restrict__ partial, int N)
{
    __shared__ int s[256];
    int t = threadIdx.x, i = blockIdx.x * 256 + t;
    s[t] = (i < N) ? counts[i] : 0;
    __syncthreads();
    #pragma unroll
    for (int off = 128; off >= 1; off >>= 1) {
        if (t < off) s[t] += s[t + off];
        __syncthreads();
    }
    if (t == 0) partial[blockIdx.x] = s[0];
}

// ---------------------------------------------------------------------------
// ks_bc: merged global+local scan -> range[i] = (start, count).
// ---------------------------------------------------------------------------
__global__ __launch_bounds__(1024) void ks_bc(
    const int* __restrict__ counts, const int* __restrict__ partial,
    int2* __restrict__ range, int N, int NB)
{
    __shared__ int sp[1024];
    __shared__ int sc[256];
    const int t = threadIdx.x;
    sp[t] = (t < NB) ? partial[t] : 0;
    __syncthreads();
    #pragma unroll
    for (int off = 1; off < 1024; off <<= 1) {
        int v = (t >= off) ? sp[t - off] : 0;
        __syncthreads();
        sp[t] += v;
        __syncthreads();
    }
    const int blockbase = (blockIdx.x == 0) ? 0 : sp[blockIdx.x - 1];

    const int i = blockIdx.x * 256 + (t & 255);
    int c = 0;
    if (t < 256) {
        c = (i < N) ? counts[i] : 0;
        sc[t] = c;
    }
    __syncthreads();
    #pragma unroll
    for (int off = 1; off < 256; off <<= 1) {
        int v = 0;
        if (t < 256 && t >= off) v = sc[t - off];
        __syncthreads();
        if (t < 256) sc[t] += v;
        __syncthreads();
    }
    if (t < 256 && i < N)
        range[i] = make_int2(blockbase + sc[t] - c, c);   // exclusive start, count
}

// ---------------------------------------------------------------------------
// kD: atomic-free CSR scatter: sorted_src[range[dst].x + rank[e]] = src.
// ---------------------------------------------------------------------------
__global__ __launch_bounds__(256) void kD_scatter(
    const int* __restrict__ ei, int E,
    const int2* __restrict__ range, const int* __restrict__ rank,
    int* __restrict__ sorted_src)
{
    int e = blockIdx.x * 256 + threadIdx.x;
    if (e < E) {
        int src = ei[e];
        int dst = ei[E + e];
        sorted_src[range[dst].x + rank[e]] = src;
    }
}

// ---------------------------------------------------------------------------
// k2: fused segment-reduce + finalize. One wave per dst node; 4 edge-slots
// of 16 lanes; lane j covers cols 8j..8j+7 via one 16B gather.
// 2-stage software pipeline (R8): next slot-group's sorted_src AND xl-gather
// issued before the current group's shuffle chain closes.
// ---------------------------------------------------------------------------
__global__ __launch_bounds__(256, 6) void k2_aggfin(
    const int2* __restrict__ range, const int* __restrict__ sorted_src,
    const unsigned short* __restrict__ xl_b,
    const unsigned short* __restrict__ xr_b,
    const unsigned short* __restrict__ sk_b,
    const float* __restrict__ att,
    const float* __restrict__ Wo, const float* __restrict__ bo,
    float* __restrict__ out, int N)
{
    const int node = (int)((blockIdx.x * (size_t)blockDim.x + threadIdx.x) >> 6);
    const int lane = threadIdx.x & 63;
    if (node >= N) return;
    const int j = lane & 15;                    // col-lane within edge slot
    const int g = lane >> 4;                    // edge slot 0..3
    const int cb = j * 8;                       // first col of this lane

    float4 a0 = *reinterpret_cast<const float4*>(att + cb);
    float4 a1 = *reinterpret_cast<const float4*>(att + cb + 4);
    float av[8] = {a0.x * LOG2E, a0.y * LOG2E, a0.z * LOG2E, a0.w * LOG2E,
                   a1.x * LOG2E, a1.y * LOG2E, a1.z * LOG2E, a1.w * LOG2E};
    float xr[8];
    unpack8(*reinterpret_cast<const uint4*>(xr_b + (size_t)node * 128 + cb), xr);

    float acc[8];
    #pragma unroll
    for (int c = 0; c < 8; ++c) acc[c] = 0.0f;
    float den = 0.0f;

    const int2 rc = range[node];
    const int total = rc.y + 1;                 // + self-loop
    const int srcbase = rc.x - 1;

    auto loadsrc = [&](int b0) -> int {
        int ii = b0 + g;
        int ic = (ii > 0 && ii < total) ? ii : 0;
        return (ic == 0) ? node : sorted_src[srcbase + ic];
    };
    auto gather = [&](int src) -> uint4 {
        return *reinterpret_cast<const uint4*>(xl_b + (size_t)src * 128 + cb);
    };

    int   sB = loadsrc(0);
    uint4 uA = gather(sB);
    sB = loadsrc(4);

    for (int b0 = 0; b0 < total; b0 += 4) {
        uint4 uB = gather(sB);                  // prefetch: next xl (1 iter ahead)
        int   sC = loadsrc(b0 + 8);             // prefetch: src after next (2 ahead)

        bool valid = (b0 + g) < total;
        float xl[8];
        unpack8(uA, xl);
        float t = 0.0f;
        #pragma unroll
        for (int c = 0; c < 8; ++c) {
            float m = xl[c] + xr[c];
            float l = fmaxf(m, NEG_SLOPE * m);  // leaky relu
            t = fmaf(l, av[c], t);
        }
        t += __shfl_xor(t, 1, 64);              // close 16-col head dot
        float e = valid ? exp2f(t) : 0.0f;
        #pragma unroll
        for (int c = 0; c < 8; ++c) acc[c] = fmaf(e, xl[c], acc[c]);
        den += e;

        uA = uB; sB = sC;
    }

    // merge the 4 edge slots (lanes +-16, +-32 hold same cols)
    #pragma unroll
    for (int c = 0; c < 8; ++c) {
        acc[c] += __shfl_xor(acc[c], 16, 64);
        acc[c] += __shfl_xor(acc[c], 32, 64);
    }
    den += __shfl_xor(den, 16, 64);
    den += __shfl_xor(den, 32, 64);

    float rd = 1.0f / (den + 1e-16f);
    float sk[8];
    unpack8(*reinterpret_cast<const uint4*>(sk_b + (size_t)node * 128 + cb), sk);
    float4 w0 = *reinterpret_cast<const float4*>(Wo + cb);
    float4 w1 = *reinterpret_cast<const float4*>(Wo + cb + 4);
    float wv[8] = {w0.x, w0.y, w0.z, w0.w, w1.x, w1.y, w1.z, w1.w};
    float s = 0.0f;
    #pragma unroll
    for (int c = 0; c < 8; ++c) {
        float gg = fmaf(acc[c], rd, sk[c]);
        float el = gg > 0.0f ? gg : (exp2f(gg * LOG2E) - 1.0f);  // elu
        s = fmaf(el, wv[c], s);
    }
    s += __shfl_xor(s, 1, 64);
    s += __shfl_xor(s, 2, 64);
    s += __shfl_xor(s, 4, 64);
    s += __shfl_xor(s, 8, 64);
    if (lane == 0) {
        float z = s + bo[0];
        out[node] = 1.0f / (1.0f + exp2f(-z * LOG2E));
    }
}

// ---------------------------------------------------------------------------
extern "C" void kernel_launch(void* const* d_in, const int* in_sizes, int n_in,
                              void* d_out, int out_size, void* d_ws, size_t ws_size,
                              hipStream_t stream) {
    const float* x   = (const float*)d_in[0];
    const float* tf  = (const float*)d_in[1];
    const int*   ei  = (const int*)  d_in[2];
    const float* Wl  = (const float*)d_in[3];
    const float* Wr  = (const float*)d_in[4];
    const float* att = (const float*)d_in[5];
    const float* bg  = (const float*)d_in[6];
    const float* Ws  = (const float*)d_in[7];
    const float* bs  = (const float*)d_in[8];
    const float* Wo  = (const float*)d_in[9];
    const float* bo  = (const float*)d_in[10];
    float* out = (float*)d_out;

    const int N = in_sizes[0] / 126;
    const int E = in_sizes[2] / 2;
    const int NB = (N + 255) / 256;     // 391 for N=100000 (must be <= 1024)

    char* ws = (char*)d_ws;
    unsigned short* Wt   = (unsigned short*)ws; ws += (size_t)384 * 128 * 2;
    unsigned short* xl_b = (unsigned short*)ws; ws += (size_t)N * 128 * 2;
    unsigned short* xr_b = (unsigned short*)ws; ws += (size_t)N * 128 * 2;
    unsigned short* sk_b = (unsigned short*)ws; ws += (size_t)N * 128 * 2;
    int*  counts   = (int*)ws;  ws += (size_t)N * 4;
    int*  partial  = (int*)ws;  ws += (size_t)1024 * 4;
    int2* range    = (int2*)ws; ws += (size_t)N * 8;
    int*  rank     = (int*)ws;  ws += (size_t)E * 4;
    int*  sorted_src = (int*)ws; ws += (size_t)E * 4;

    // 1: weight pack + zero counts
    hipLaunchKernelGGL(kA_prep, dim3(192 + (N + 255) / 256), dim3(256), 0, stream,
                       Wl, Wr, Ws, Wt, counts, N);
    // 2: histogram+rank fused with node GEMM (GEMM is the floor; hist hides)
    const int GB = (N + 31) / 32;
    hipLaunchKernelGGL(kB_hist_gemm, dim3(KB_HB + GB), dim3(256), 0, stream,
                       ei, E, counts, rank, x, tf, Wt, bg, bs,
                       xl_b, xr_b, sk_b, N);
    // 3-4: scan -> range(start,count)
    hipLaunchKernelGGL(ks_a, dim3(NB), dim3(256), 0, stream, counts, partial, N);
    hipLaunchKernelGGL(ks_bc, dim3(NB), dim3(1024), 0, stream,
                       counts, partial, range, N, NB);
    // 5: atomic-free scatter
    hipLaunchKernelGGL(kD_scatter, dim3((E + 255) / 256), dim3(256), 0, stream,
                       ei, E, range, rank, sorted_src);
    // 6: segment-reduce + finalize (pipelined gathers)
    hipLaunchKernelGGL(k2_aggfin, dim3((N + 3) / 4), dim3(256), 0, stream,
                       range, sorted_src, xl_b, xr_b, sk_b,
                       att, Wo, bo, out, N);
}